// Round 1
// baseline (234.134 us; speedup 1.0000x reference)
//
#include <hip/hip_runtime.h>
#include <hip/hip_bf16.h>

// Problem constants (SubClusteringNet): N=131072, K=16, IN=256, OUT=128
#define KEXP   16
#define IN_DIM 256
#define OUT_DIM 128

typedef float f32x4 __attribute__((ext_vector_type(4)));
typedef short bf16x8 __attribute__((ext_vector_type(8)));

__device__ __forceinline__ short f2bf(float f) {
    union { float f; unsigned u; } v; v.f = f;
    unsigned r = (v.u + 0x7fffu + ((v.u >> 16) & 1u)) >> 16;  // RNE
    return (short)r;
}

// ---------------- pass 1: histogram of z ----------------
__global__ __launch_bounds__(256) void hist_k(const int* __restrict__ z,
                                              int* __restrict__ counts, int n) {
    __shared__ int h[KEXP];
    if (threadIdx.x < KEXP) h[threadIdx.x] = 0;
    __syncthreads();
    int stride = gridDim.x * blockDim.x;
    for (int i = blockIdx.x * blockDim.x + threadIdx.x; i < n; i += stride)
        atomicAdd(&h[z[i]], 1);
    __syncthreads();
    if (threadIdx.x < KEXP) atomicAdd(&counts[threadIdx.x], h[threadIdx.x]);
}

// ---------------- pass 2: exclusive scan (tiny) ----------------
__global__ void scan_k(const int* __restrict__ counts, int* __restrict__ bases,
                       int* __restrict__ tb) {
    if (threadIdx.x == 0) {
        int acc = 0, tacc = 0;
        for (int i = 0; i < KEXP; i++) {
            bases[i] = acc;
            tb[i] = tacc;
            acc += counts[i];
            tacc += (counts[i] + 63) >> 6;
        }
        tb[KEXP] = tacc;
    }
}

// ---------------- pass 3: scatter perm (tokens grouped by expert) ----------------
__global__ __launch_bounds__(256) void scatter_k(const int* __restrict__ z,
                                                 const int* __restrict__ bases,
                                                 int* __restrict__ cursors,
                                                 int* __restrict__ perm, int n) {
    __shared__ int lc[KEXP];
    __shared__ int lb[KEXP];
    int tid = threadIdx.x;
    if (tid < KEXP) lc[tid] = 0;
    __syncthreads();
    int i = blockIdx.x * 256 + tid;
    int e = 0, r = 0;
    if (i < n) {
        e = z[i];
        r = atomicAdd(&lc[e], 1);
    }
    __syncthreads();
    if (tid < KEXP && lc[tid] > 0) lb[tid] = atomicAdd(&cursors[tid], lc[tid]);
    __syncthreads();
    if (i < n) perm[bases[e] + lb[e] + r] = i;
}

// ---------------- pass 4: W1 [K][256][128] f32 -> W1^T [K][128][256] bf16 ----------------
__global__ __launch_bounds__(256) void tw1_k(const float* __restrict__ W1,
                                             ushort* __restrict__ w1t) {
    __shared__ float ld[64][65];
    int bid = blockIdx.x;              // 16 experts * 4 k-tiles * 2 n-tiles = 128
    int e = bid >> 3, sub = bid & 7;
    int k0 = (sub & 3) * 64, n0 = (sub >> 2) * 64;
    const float* src = W1 + (long)e * IN_DIM * OUT_DIM;   // [256][128]
    int tid = threadIdx.x;
    int tr = tid >> 6, tc = tid & 63;
#pragma unroll
    for (int i = 0; i < 16; i++) {
        int row = i * 4 + tr;
        ld[row][tc] = src[(k0 + row) * OUT_DIM + n0 + tc];
    }
    __syncthreads();
    ushort* dst = w1t + (long)e * OUT_DIM * IN_DIM;       // [128][256]
#pragma unroll
    for (int i = 0; i < 16; i++) {
        int nrow = i * 4 + tr;
        dst[(n0 + nrow) * IN_DIM + k0 + tc] = (ushort)f2bf(ld[tc][nrow]);
    }
}

// ---------------- pass 5: grouped GEMM + fused MLP head + softmax ----------------
// Block: 256 thr = 4 waves; 64 tokens x 128 outs; K=256 in two 128-chunks.
// LDS: W1^T chunk [128 cols][128 k] bf16 = 32 KB, XOR-swizzled (G4).
__global__ __launch_bounds__(256) void mlp_k(
    const float* __restrict__ x, const float* __restrict__ b1,
    const float* __restrict__ W2, const float* __restrict__ b2,
    const int* __restrict__ counts, const int* __restrict__ bases,
    const int* __restrict__ tb, const int* __restrict__ perm,
    const ushort* __restrict__ w1t, float* __restrict__ out) {
    __shared__ char smem[32768];
    int b = blockIdx.x;
    if (b >= tb[KEXP]) return;
    int e = 0;
#pragma unroll
    for (int i = 1; i < KEXP; i++)
        if (b >= tb[i]) e = i;
    int t = b - tb[e];
    int nrem = counts[e] - t * 64;          // >= 1 for a live tile
    int pbase = bases[e] + t * 64;

    int tid = threadIdx.x;
    int lane = tid & 63, wid = tid >> 6;
    int li = lane & 15, q = lane >> 4;

    // A-row gather index: wave wid owns tokens wid*16 .. wid*16+15
    int mlane = wid * 16 + li;
    int gidx = perm[pbase + (mlane < nrem ? mlane : 0)];
    const float* xrow = x + (long)gidx * IN_DIM;

    const ushort* wsrc = w1t + (long)e * (OUT_DIM * IN_DIM);

    f32x4 acc[8];
#pragma unroll
    for (int n = 0; n < 8; n++) acc[n] = (f32x4)0.0f;

#pragma unroll
    for (int kt = 0; kt < 2; kt++) {
        __syncthreads();  // protect previous chunk reads before overwrite
        // stage W1^T rows (out-cols) 0..127, k in [kt*128, kt*128+128), 16B granules
        for (int i = tid; i < 2048; i += 256) {
            int byte = i * 16;
            int row = byte >> 8;            // out col
            int inrow = byte & 255;         // byte within 128-k slice
            uint4 v = *(const uint4*)((const char*)wsrc + (long)row * 512 + kt * 256 + inrow);
            *(uint4*)(smem + (byte ^ ((row & 7) << 4))) = v;
        }
        __syncthreads();

#pragma unroll
        for (int kk = 0; kk < 4; kk++) {
            int k0 = kt * 128 + kk * 32 + q * 8;
            f32x4 a0 = *(const f32x4*)(xrow + k0);
            f32x4 a1 = *(const f32x4*)(xrow + k0 + 4);
            bf16x8 af;
            af[0] = f2bf(a0[0]); af[1] = f2bf(a0[1]); af[2] = f2bf(a0[2]); af[3] = f2bf(a0[3]);
            af[4] = f2bf(a1[0]); af[5] = f2bf(a1[1]); af[6] = f2bf(a1[2]); af[7] = f2bf(a1[3]);
#pragma unroll
            for (int n = 0; n < 8; n++) {
                int col = n * 16 + li;
                int byte = col * 256 + kk * 64 + q * 16;
                bf16x8 bfv = *(const bf16x8*)(smem + (byte ^ ((col & 7) << 4)));
                acc[n] = __builtin_amdgcn_mfma_f32_16x16x32_bf16(af, bfv, acc[n], 0, 0, 0);
            }
        }
    }

    // Epilogue: h = relu(acc + b1); logits = h @ W2 + b2; softmax; scatter out.
    // lane holds h[m=(q*4+r)][col=n*16+li]; reduce over li (16-lane butterfly).
    float p0[4] = {0.f, 0.f, 0.f, 0.f}, p1[4] = {0.f, 0.f, 0.f, 0.f};
#pragma unroll
    for (int n = 0; n < 8; n++) {
        int col = n * 16 + li;
        float bb = b1[e * OUT_DIM + col];
        float w0 = W2[e * OUT_DIM * 2 + col * 2 + 0];
        float w1 = W2[e * OUT_DIM * 2 + col * 2 + 1];
#pragma unroll
        for (int r = 0; r < 4; r++) {
            float h = acc[n][r] + bb;
            h = fmaxf(h, 0.0f);
            p0[r] += h * w0;
            p1[r] += h * w1;
        }
    }
#pragma unroll
    for (int m = 1; m < 16; m <<= 1) {
#pragma unroll
        for (int r = 0; r < 4; r++) {
            p0[r] += __shfl_xor(p0[r], m, 64);
            p1[r] += __shfl_xor(p1[r], m, 64);
        }
    }
    if (li == 0) {
        float bb0 = b2[e * 2], bb1 = b2[e * 2 + 1];
#pragma unroll
        for (int r = 0; r < 4; r++) {
            int mm = wid * 16 + q * 4 + r;
            if (mm < nrem) {
                int orig = perm[pbase + mm];
                float l0 = p0[r] + bb0, l1 = p1[r] + bb1;
                float mx = fmaxf(l0, l1);
                float e0 = __expf(l0 - mx), e1 = __expf(l1 - mx);
                float inv = 1.0f / (e0 + e1);
                float2 o = make_float2(e0 * inv, e1 * inv);
                *(float2*)(out + (long)orig * 2) = o;
            }
        }
    }
}

extern "C" void kernel_launch(void* const* d_in, const int* in_sizes, int n_in,
                              void* d_out, int out_size, void* d_ws, size_t ws_size,
                              hipStream_t stream) {
    const float* x  = (const float*)d_in[0];
    const int*   z  = (const int*)d_in[1];
    const float* W1 = (const float*)d_in[2];
    const float* b1 = (const float*)d_in[3];
    const float* W2 = (const float*)d_in[4];
    const float* b2 = (const float*)d_in[5];
    float* out = (float*)d_out;
    int n = in_sizes[1];                    // 131072 tokens

    // ws layout: [counts 16][cursors 16][bases 16][tb 17] ... perm[n] @1024 ... w1t bf16
    int* counts  = (int*)d_ws;
    int* cursors = counts + 16;
    int* basesp  = counts + 32;
    int* tbp     = counts + 48;
    int* perm    = counts + 256;                                  // byte offset 1024
    ushort* w1t  = (ushort*)((char*)d_ws + 1024 + (size_t)n * 4); // 16B-aligned

    hipMemsetAsync(counts, 0, 256, stream);                       // counts + cursors
    hist_k<<<256, 256, 0, stream>>>(z, counts, n);
    scan_k<<<1, 64, 0, stream>>>(counts, basesp, tbp);
    scatter_k<<<(n + 255) / 256, 256, 0, stream>>>(z, basesp, cursors, perm, n);
    tw1_k<<<KEXP * 8, 256, 0, stream>>>(W1, w1t);

    int maxtiles = (n + 63) / 64 + (KEXP - 1);                    // sum ceil(n_e/64) bound
    mlp_k<<<maxtiles, 256, 0, stream>>>(x, b1, W2, b2, counts, basesp, tbp, perm, w1t, out);
}